// Round 8
// baseline (282.957 us; speedup 1.0000x reference)
//
#include <hip/hip_runtime.h>
#include <math.h>

// Color NGP, three-phase:
//   Phase 0 (convert): f32 table -> packed bf16 (u32/entry) in ws, XCD-pinned
//     so each XCD converts the 2 level slices (4MB bf16) it will gather from
//     -> slice is L2-resident at write time. Halves gather line traffic.
//   Phase A (encode): XCD-pinned level-major grid (XCD x -> levels 2x,2x+1);
//     16 random 4B gathers/point/level from the XCD-resident bf16 slice.
//     enc written as packed bf16 pairs (u32) [L][P], nontemporal.
//   Phase B (MLP, MFMA): 256 pts/block, 4 waves; GEMM1->GELU->LDS(swizzled)
//     ->GEMM2->GELU->LDS->GEMM3 with mfma_f32_16x16x32_bf16. (~15us)
//   Round-7 lesson: FETCH 307->86MB with no dur change => encode is bound by
//     L2 line traffic or TA request rate, not HBM. This round halves line
//     traffic at constant request count to discriminate.
// Fallbacks: f32-table two-phase path (ws >= 16.8MB), else fused VALU kernel.

#define NLEV 16
#define TSIZE (1u << 19)
#define TMASK (TSIZE - 1u)
#define NXCD 8

typedef __attribute__((ext_vector_type(8))) short bf16x8;
typedef __attribute__((ext_vector_type(4))) float f32x4;

union U32x4 { unsigned u[4]; uint4 q; bf16x8 v; };

// round-to-nearest-even f32 -> bf16 bits
__device__ __forceinline__ unsigned bfr(float x) {
    unsigned u = __float_as_uint(x);
    return (u + 0x7FFFu + ((u >> 16) & 1u)) >> 16;
}

// exact-GELU via A&S 7.1.26 erf (|eps| <= 1.5e-7)
__device__ __forceinline__ float gelu_fast(float x) {
    float ax = fabsf(x) * 0.70710678118654752440f;
    float t  = __builtin_amdgcn_rcpf(fmaf(0.3275911f, ax, 1.0f));
    float p  = t * (0.254829592f + t * (-0.284496736f + t * (1.421413741f +
               t * (-1.453152027f + t * 1.061405429f))));
    float e  = __expf(-ax * ax);
    float er = fmaf(-p, e, 1.0f);
    er = copysignf(er, x);
    return 0.5f * x * (1.0f + er);
}

__device__ __forceinline__ float gelu_exact(float x) {
    return 0.5f * x * (1.0f + erff(x * 0.70710678118654752440f));
}

// ---------------- Phase 0: table f32 -> packed bf16, XCD-pinned ----------------
// grid = 16384 blocks: xcd = bid&7 handles levels {2x, 2x+1}; 1024 chunks/level,
// 512 entries/chunk (256 threads x 2 entries).
__global__ __launch_bounds__(256) void ngp_convert(
    const float4* __restrict__ table4,   // [16*T/2] float4 = 2 entries
    uint2* __restrict__ tabb2)           // [16*T/2] uint2  = 2 entries
{
    const int bid = blockIdx.x;
    const int xcd = bid & (NXCD - 1);
    const int j   = bid >> 3;                       // 0..2047
    const int l   = xcd * 2 + (j >> 10);
    const int chunk = j & 1023;
    const int idx2 = (l * (int)TSIZE + chunk * 512) >> 1;  // float4/uint2 index
    const int i = idx2 + threadIdx.x;
    const float4 v = table4[i];
    tabb2[i] = make_uint2(bfr(v.x) | (bfr(v.y) << 16),
                          bfr(v.z) | (bfr(v.w) << 16));
}

// ---------------- Phase A: encode from bf16 table, XCD-pinned ----------------
__global__ __launch_bounds__(256, 6) void ngp_encode_b(
    const float* __restrict__ inputs,   // [B,N,3]
    const float* __restrict__ latent,   // [B,1]
    const unsigned* __restrict__ tabb,  // [16][T] packed bf16 pair
    unsigned* __restrict__ encb,        // [L][P] packed bf16 pair
    int P, int bplShift, int nShift)
{
    const int bid = blockIdx.x;
    const int xcd = bid & (NXCD - 1);
    const int j   = bid >> 3;
    const int l   = xcd * (NLEV / NXCD) + (j >> bplShift);
    const int p   = ((j & ((1 << bplShift) - 1)) << 8) + threadIdx.x;

    float x0 = inputs[p * 3 + 0];
    float x1 = inputs[p * 3 + 1];
    float x2 = inputs[p * 3 + 2];
    float x3 = latent[p >> nShift];
    x0 = (x0 + 1.0f) * 0.5f;
    x1 = (x1 + 1.0f) * 0.5f;
    x2 = (x2 + 1.0f) * 0.5f;
    x3 = (x3 + 1.0f) * 0.5f;

    const float LOG2S = (float)log2(1.3819);
    const float s = exp2f((float)l * LOG2S) * 16.0f - 1.0f;

    const float px = fmaf(x0, s, 0.5f);
    const float py = fmaf(x1, s, 0.5f);
    const float pz = fmaf(x2, s, 0.5f);
    const float pw = fmaf(x3, s, 0.5f);
    const float fx = floorf(px), fy = floorf(py), fz = floorf(pz), fw = floorf(pw);
    const float rx = px - fx, ry = py - fy, rz = pz - fz, rw = pw - fw;

    const unsigned a0 = (unsigned)(int)fx;               const unsigned a1 = a0 + 1u;
    const unsigned b0 = (unsigned)(int)fy * 2654435761u; const unsigned b1v = b0 + 2654435761u;
    const unsigned c0 = (unsigned)(int)fz * 805459861u;  const unsigned c1 = c0 + 805459861u;
    const unsigned d0 = (unsigned)(int)fw * 3674653429u; const unsigned d1 = d0 + 3674653429u;

    const float wx0 = 1.0f - rx, wy0 = 1.0f - ry, wz0 = 1.0f - rz, ww0 = 1.0f - rw;
    const float wxy[4] = { wx0 * wy0, rx * wy0, wx0 * ry, rx * ry };
    const float wzw[4] = { wz0 * ww0, rz * ww0, wz0 * rw, rz * rw };

    const unsigned* __restrict__ tl = tabb + (unsigned)l * TSIZE;

    float acc0 = 0.0f, acc1 = 0.0f;
    #pragma unroll
    for (int c = 0; c < 16; ++c) {
        unsigned h = ((c & 1) ? a1 : a0) ^ ((c & 2) ? b1v : b0)
                   ^ ((c & 4) ? c1 : c0) ^ ((c & 8) ? d1 : d0);
        const unsigned e = tl[h & TMASK];
        const float v0 = __uint_as_float(e << 16);
        const float v1 = __uint_as_float(e & 0xFFFF0000u);
        const float wgt = wxy[c & 3] * wzw[c >> 2];
        acc0 = fmaf(wgt, v0, acc0);
        acc1 = fmaf(wgt, v1, acc1);
    }
    __builtin_nontemporal_store(bfr(acc0) | (bfr(acc1) << 16), &encb[l * P + p]);
}

// ---------------- Phase A fallback: encode from f32 table ----------------
__global__ __launch_bounds__(256, 6) void ngp_encode(
    const float* __restrict__ inputs,
    const float* __restrict__ latent,
    const float* __restrict__ table,
    unsigned* __restrict__ encb,
    int P, int bplShift, int nShift)
{
    const int bid = blockIdx.x;
    const int xcd = bid & (NXCD - 1);
    const int j   = bid >> 3;
    const int l   = xcd * (NLEV / NXCD) + (j >> bplShift);
    const int p   = ((j & ((1 << bplShift) - 1)) << 8) + threadIdx.x;

    float x0 = inputs[p * 3 + 0];
    float x1 = inputs[p * 3 + 1];
    float x2 = inputs[p * 3 + 2];
    float x3 = latent[p >> nShift];
    x0 = (x0 + 1.0f) * 0.5f;
    x1 = (x1 + 1.0f) * 0.5f;
    x2 = (x2 + 1.0f) * 0.5f;
    x3 = (x3 + 1.0f) * 0.5f;

    const float LOG2S = (float)log2(1.3819);
    const float s = exp2f((float)l * LOG2S) * 16.0f - 1.0f;

    const float px = fmaf(x0, s, 0.5f);
    const float py = fmaf(x1, s, 0.5f);
    const float pz = fmaf(x2, s, 0.5f);
    const float pw = fmaf(x3, s, 0.5f);
    const float fx = floorf(px), fy = floorf(py), fz = floorf(pz), fw = floorf(pw);
    const float rx = px - fx, ry = py - fy, rz = pz - fz, rw = pw - fw;

    const unsigned a0 = (unsigned)(int)fx;               const unsigned a1 = a0 + 1u;
    const unsigned b0 = (unsigned)(int)fy * 2654435761u; const unsigned b1v = b0 + 2654435761u;
    const unsigned c0 = (unsigned)(int)fz * 805459861u;  const unsigned c1 = c0 + 805459861u;
    const unsigned d0 = (unsigned)(int)fw * 3674653429u; const unsigned d1 = d0 + 3674653429u;

    const float wx0 = 1.0f - rx, wy0 = 1.0f - ry, wz0 = 1.0f - rz, ww0 = 1.0f - rw;
    const float wxy[4] = { wx0 * wy0, rx * wy0, wx0 * ry, rx * ry };
    const float wzw[4] = { wz0 * ww0, rz * ww0, wz0 * rw, rz * rw };

    const float2* __restrict__ tab2 = (const float2*)table;
    const unsigned base = (unsigned)l * TSIZE;

    float acc0 = 0.0f, acc1 = 0.0f;
    #pragma unroll
    for (int c = 0; c < 16; ++c) {
        unsigned h = ((c & 1) ? a1 : a0) ^ ((c & 2) ? b1v : b0)
                   ^ ((c & 4) ? c1 : c0) ^ ((c & 8) ? d1 : d0);
        const float2 v = tab2[base + (h & TMASK)];
        const float wgt = wxy[c & 3] * wzw[c >> 2];
        acc0 = fmaf(wgt, v.x, acc0);
        acc1 = fmaf(wgt, v.y, acc1);
    }
    __builtin_nontemporal_store(bfr(acc0) | (bfr(acc1) << 16), &encb[l * P + p]);
}

// ---------------- Phase B: MFMA MLP 32->64->64->3 ----------------
__global__ __launch_bounds__(256) void ngp_mlp_mfma(
    const unsigned* __restrict__ encb,  // [L][P] packed bf16 pair
    const float* __restrict__ W1, const float* __restrict__ b1,   // [32,64],[64]
    const float* __restrict__ W2, const float* __restrict__ b2,   // [64,64],[64]
    const float* __restrict__ W3, const float* __restrict__ b3,   // [64,3],[3]
    float* __restrict__ out, int P)
{
    __shared__ __align__(16) unsigned char sH[4 * 8192];  // 4 waves x 64pt x 64n x bf16

    const int tid  = threadIdx.x;
    const int w    = tid >> 6;
    const int lane = tid & 63;
    const int lo16 = lane & 15;
    const int hi4  = lane >> 4;          // lane group 0..3
    const int pbase = blockIdx.x * 256 + w * 64;
    char* const myH = (char*)sH + w * 8192;

    // ---- A-fragments (bf16) for W1^T, W2^T, W3^T ----
    bf16x8 w1f[4];
    #pragma unroll
    for (int mt = 0; mt < 4; ++mt) {
        const int m = mt * 16 + lo16;
        const int kg = hi4 * 8;
        bf16x8 f;
        #pragma unroll
        for (int j = 0; j < 4; ++j) {
            f[2 * j    ] = (short)bfr(W1[(kg + 2 * j    ) * 64 + m]);
            f[2 * j + 1] = (short)bfr(W1[(kg + 2 * j + 1) * 64 + m]);
        }
        w1f[mt] = f;
    }
    bf16x8 w2f[4][2];
    #pragma unroll
    for (int mt = 0; mt < 4; ++mt) {
        const int m = mt * 16 + lo16;
        #pragma unroll
        for (int kc = 0; kc < 2; ++kc) {
            const int kg = kc * 32 + hi4 * 8;
            bf16x8 f;
            #pragma unroll
            for (int j = 0; j < 4; ++j) {
                f[2 * j    ] = (short)bfr(W2[(kg + 2 * j    ) * 64 + m]);
                f[2 * j + 1] = (short)bfr(W2[(kg + 2 * j + 1) * 64 + m]);
            }
            w2f[mt][kc] = f;
        }
    }
    bf16x8 w3f[2];
    {
        const int m = (lo16 < 3) ? lo16 : 2;
        #pragma unroll
        for (int kc = 0; kc < 2; ++kc) {
            const int kg = kc * 32 + hi4 * 8;
            bf16x8 f;
            #pragma unroll
            for (int j = 0; j < 4; ++j) {
                f[2 * j    ] = (short)bfr(W3[(kg + 2 * j    ) * 3 + m]);
                f[2 * j + 1] = (short)bfr(W3[(kg + 2 * j + 1) * 3 + m]);
            }
            w3f[kc] = f;
        }
    }

    const f32x4 zero = {0.0f, 0.0f, 0.0f, 0.0f};

    // ---- GEMM1 ----
    f32x4 acc1[4][4];
    #pragma unroll
    for (int mt = 0; mt < 4; ++mt)
        #pragma unroll
        for (int nt = 0; nt < 4; ++nt) acc1[mt][nt] = zero;

    #pragma unroll
    for (int nt = 0; nt < 4; ++nt) {
        const int p = pbase + nt * 16 + lo16;
        const int lev0 = hi4 * 4;
        U32x4 bu;
        #pragma unroll
        for (int j = 0; j < 4; ++j) bu.u[j] = encb[(lev0 + j) * P + p];
        #pragma unroll
        for (int mt = 0; mt < 4; ++mt)
            acc1[mt][nt] = __builtin_amdgcn_mfma_f32_16x16x32_bf16(
                w1f[mt], bu.v, acc1[mt][nt], 0, 0, 0);
    }

    // ---- epilogue 1 ----
    float4 b1v[4];
    #pragma unroll
    for (int mt = 0; mt < 4; ++mt)
        b1v[mt] = *(const float4*)(b1 + mt * 16 + hi4 * 4);

    #pragma unroll
    for (int mt = 0; mt < 4; ++mt) {
        const int nb  = mt * 16 + hi4 * 4;
        const int blkb = nb >> 3;
        #pragma unroll
        for (int nt = 0; nt < 4; ++nt) {
            const f32x4 a = acc1[mt][nt];
            const float h0 = gelu_fast(a[0] + b1v[mt].x);
            const float h1 = gelu_fast(a[1] + b1v[mt].y);
            const float h2 = gelu_fast(a[2] + b1v[mt].z);
            const float h3 = gelu_fast(a[3] + b1v[mt].w);
            const int pl = nt * 16 + lo16;
            char* dst = myH + pl * 128 + ((blkb ^ (pl & 7)) * 16) + ((nb & 7) * 2);
            *(uint2*)dst = make_uint2(bfr(h0) | (bfr(h1) << 16),
                                      bfr(h2) | (bfr(h3) << 16));
        }
    }

    // ---- GEMM2 ----
    f32x4 acc2[4][4];
    #pragma unroll
    for (int mt = 0; mt < 4; ++mt)
        #pragma unroll
        for (int nt = 0; nt < 4; ++nt) acc2[mt][nt] = zero;

    #pragma unroll
    for (int kc = 0; kc < 2; ++kc) {
        #pragma unroll
        for (int nt = 0; nt < 4; ++nt) {
            const int pl = nt * 16 + lo16;
            const int kb = kc * 4 + hi4;
            const char* src = myH + pl * 128 + ((kb ^ (pl & 7)) * 16);
            U32x4 bu; bu.q = *(const uint4*)src;
            #pragma unroll
            for (int mt = 0; mt < 4; ++mt)
                acc2[mt][nt] = __builtin_amdgcn_mfma_f32_16x16x32_bf16(
                    w2f[mt][kc], bu.v, acc2[mt][nt], 0, 0, 0);
        }
    }

    // ---- epilogue 2 ----
    float4 b2v[4];
    #pragma unroll
    for (int mt = 0; mt < 4; ++mt)
        b2v[mt] = *(const float4*)(b2 + mt * 16 + hi4 * 4);

    #pragma unroll
    for (int mt = 0; mt < 4; ++mt) {
        const int nb  = mt * 16 + hi4 * 4;
        const int blkb = nb >> 3;
        #pragma unroll
        for (int nt = 0; nt < 4; ++nt) {
            const f32x4 a = acc2[mt][nt];
            const float h0 = gelu_fast(a[0] + b2v[mt].x);
            const float h1 = gelu_fast(a[1] + b2v[mt].y);
            const float h2 = gelu_fast(a[2] + b2v[mt].z);
            const float h3 = gelu_fast(a[3] + b2v[mt].w);
            const int pl = nt * 16 + lo16;
            char* dst = myH + pl * 128 + ((blkb ^ (pl & 7)) * 16) + ((nb & 7) * 2);
            *(uint2*)dst = make_uint2(bfr(h0) | (bfr(h1) << 16),
                                      bfr(h2) | (bfr(h3) << 16));
        }
    }

    // ---- GEMM3 ----
    f32x4 acc3[4];
    #pragma unroll
    for (int nt = 0; nt < 4; ++nt) acc3[nt] = zero;

    #pragma unroll
    for (int kc = 0; kc < 2; ++kc) {
        #pragma unroll
        for (int nt = 0; nt < 4; ++nt) {
            const int pl = nt * 16 + lo16;
            const int kb = kc * 4 + hi4;
            const char* src = myH + pl * 128 + ((kb ^ (pl & 7)) * 16);
            U32x4 bu; bu.q = *(const uint4*)src;
            acc3[nt] = __builtin_amdgcn_mfma_f32_16x16x32_bf16(
                w3f[kc], bu.v, acc3[nt], 0, 0, 0);
        }
    }

    const float b30 = b3[0], b31 = b3[1], b32 = b3[2];
    if (hi4 == 0) {
        #pragma unroll
        for (int nt = 0; nt < 4; ++nt) {
            const int p = pbase + nt * 16 + lo16;
            out[p * 3 + 0] = acc3[nt][0] + b30;
            out[p * 3 + 1] = acc3[nt][1] + b31;
            out[p * 3 + 2] = acc3[nt][2] + b32;
        }
    }
}

// ---------------- Fallback: fused single kernel (if ws too small) ----------------
__global__ __launch_bounds__(256) void ngp_fused(
    const float* __restrict__ inputs, const float* __restrict__ latent,
    const float* __restrict__ table,
    const float* __restrict__ W1, const float* __restrict__ b1,
    const float* __restrict__ W2, const float* __restrict__ b2,
    const float* __restrict__ W3, const float* __restrict__ b3,
    float* __restrict__ out)
{
    const int p = blockIdx.x * 256 + threadIdx.x;
    float x0 = inputs[p * 3 + 0];
    float x1 = inputs[p * 3 + 1];
    float x2 = inputs[p * 3 + 2];
    float x3 = latent[p >> 15];
    x0 = (x0 + 1.0f) * 0.5f; x1 = (x1 + 1.0f) * 0.5f;
    x2 = (x2 + 1.0f) * 0.5f; x3 = (x3 + 1.0f) * 0.5f;

    float h1[64];
    #pragma unroll
    for (int j = 0; j < 64; ++j) h1[j] = 0.0f;

    const float LOG2S = (float)log2(1.3819);
    const float2* __restrict__ tab2 = (const float2*)table;

    #pragma unroll 2
    for (int l = 0; l < NLEV; ++l) {
        const float s = exp2f((float)l * LOG2S) * 16.0f - 1.0f;
        const float px = fmaf(x0, s, 0.5f);
        const float py = fmaf(x1, s, 0.5f);
        const float pz = fmaf(x2, s, 0.5f);
        const float pw = fmaf(x3, s, 0.5f);
        const float fx = floorf(px), fy = floorf(py), fz = floorf(pz), fw = floorf(pw);
        const float rx = px - fx, ry = py - fy, rz = pz - fz, rw = pw - fw;
        const unsigned a0 = (unsigned)(int)fx;               const unsigned a1 = a0 + 1u;
        const unsigned b0 = (unsigned)(int)fy * 2654435761u; const unsigned b1v = b0 + 2654435761u;
        const unsigned c0 = (unsigned)(int)fz * 805459861u;  const unsigned c1 = c0 + 805459861u;
        const unsigned d0 = (unsigned)(int)fw * 3674653429u; const unsigned d1 = d0 + 3674653429u;
        const float wx0 = 1.0f - rx, wy0 = 1.0f - ry, wz0 = 1.0f - rz, ww0 = 1.0f - rw;
        const float wxy[4] = { wx0 * wy0, rx * wy0, wx0 * ry, rx * ry };
        const float wzw[4] = { wz0 * ww0, rz * ww0, wz0 * rw, rz * rw };
        const unsigned base = (unsigned)l * TSIZE;
        float acc0 = 0.0f, acc1 = 0.0f;
        #pragma unroll
        for (int c = 0; c < 16; ++c) {
            unsigned h = ((c & 1) ? a1 : a0) ^ ((c & 2) ? b1v : b0)
                       ^ ((c & 4) ? c1 : c0) ^ ((c & 8) ? d1 : d0);
            const float2 v = tab2[base + (h & TMASK)];
            const float wgt = wxy[c & 3] * wzw[c >> 2];
            acc0 = fmaf(wgt, v.x, acc0);
            acc1 = fmaf(wgt, v.y, acc1);
        }
        const float* __restrict__ w0 = W1 + (2 * l) * 64;
        const float* __restrict__ w1 = W1 + (2 * l + 1) * 64;
        #pragma unroll
        for (int j = 0; j < 64; ++j) {
            h1[j] = fmaf(acc0, w0[j], fmaf(acc1, w1[j], h1[j]));
        }
    }
    #pragma unroll
    for (int j = 0; j < 64; ++j) h1[j] = gelu_exact(h1[j] + b1[j]);

    float col0 = b3[0], col1 = b3[1], col2 = b3[2];
    #pragma unroll 1
    for (int ch = 0; ch < 8; ++ch) {
        float acc[8];
        #pragma unroll
        for (int k = 0; k < 8; ++k) acc[k] = b2[ch * 8 + k];
        #pragma unroll
        for (int i = 0; i < 64; ++i) {
            const float hv = h1[i];
            const float* __restrict__ wr = W2 + i * 64 + ch * 8;
            #pragma unroll
            for (int k = 0; k < 8; ++k) acc[k] = fmaf(hv, wr[k], acc[k]);
        }
        #pragma unroll
        for (int k = 0; k < 8; ++k) {
            const float g = gelu_exact(acc[k]);
            const int j2 = ch * 8 + k;
            col0 = fmaf(g, W3[j2 * 3 + 0], col0);
            col1 = fmaf(g, W3[j2 * 3 + 1], col1);
            col2 = fmaf(g, W3[j2 * 3 + 2], col2);
        }
    }
    out[p * 3 + 0] = col0;
    out[p * 3 + 1] = col1;
    out[p * 3 + 2] = col2;
}

extern "C" void kernel_launch(void* const* d_in, const int* in_sizes, int n_in,
                              void* d_out, int out_size, void* d_ws, size_t ws_size,
                              hipStream_t stream) {
    const float* inputs = (const float*)d_in[0];
    const float* latent = (const float*)d_in[1];
    const float* table  = (const float*)d_in[2];
    const float* W1 = (const float*)d_in[3];
    const float* b1 = (const float*)d_in[4];
    const float* W2 = (const float*)d_in[5];
    const float* b2 = (const float*)d_in[6];
    const float* W3 = (const float*)d_in[7];
    const float* b3 = (const float*)d_in[8];
    float* out = (float*)d_out;

    const int P = in_sizes[0] / 3;              // 262144
    const int B = in_sizes[1];                  // 8
    const int N = P / B;                        // 32768
    const int nShift = 31 - __builtin_clz(N);   // 15
    const int bpl = P / 256;                    // 1024 blocks per level
    const int bplShift = 31 - __builtin_clz(bpl);

    const size_t encBytes = (size_t)P * NLEV * sizeof(unsigned);        // 16.8 MB
    const size_t tabBytes = (size_t)NLEV * TSIZE * sizeof(unsigned);    // 32 MB
    const bool shapeOK = (P & 255) == 0 && (bpl & (bpl - 1)) == 0 &&
                         (N & (N - 1)) == 0 && bpl >= 8;

    if (shapeOK && ws_size >= encBytes + tabBytes) {
        unsigned* encb = (unsigned*)d_ws;
        unsigned* tabb = (unsigned*)((char*)d_ws + encBytes);
        ngp_convert<<<dim3(16384), dim3(256), 0, stream>>>(
            (const float4*)table, (uint2*)tabb);
        ngp_encode_b<<<dim3(bpl * NLEV), dim3(256), 0, stream>>>(
            inputs, latent, tabb, encb, P, bplShift, nShift);
        ngp_mlp_mfma<<<dim3(P / 256), dim3(256), 0, stream>>>(
            encb, W1, b1, W2, b2, W3, b3, out, P);
    } else if (shapeOK && ws_size >= encBytes) {
        unsigned* encb = (unsigned*)d_ws;
        ngp_encode<<<dim3(bpl * NLEV), dim3(256), 0, stream>>>(
            inputs, latent, table, encb, P, bplShift, nShift);
        ngp_mlp_mfma<<<dim3(P / 256), dim3(256), 0, stream>>>(
            encb, W1, b1, W2, b2, W3, b3, out, P);
    } else {
        ngp_fused<<<dim3(P / 256), dim3(256), 0, stream>>>(
            inputs, latent, table, W1, b1, W2, b2, W3, b3, out);
    }
}

// Round 9
// 203.722 us; speedup vs baseline: 1.3889x; 1.3889x over previous
//
#include <hip/hip_runtime.h>
#include <math.h>

// Color NGP, two-phase:
//   Phase A (encode): XCD-pinned level-major grid (XCD x -> levels 2x,2x+1 via
//     dispatch bid%8). Gather-REQUEST-count optimized: _PRIMES[0]==1, so the
//     corner pair differing in dim-0 offset has masked indices {2k,2k+1}
//     whenever ix is even -> ONE aligned 16B load covers both corners.
//     Expected 12 requests/point-level instead of 16 (round 7/8 showed the
//     encode is L2-request-rate bound: line-traffic halving changed nothing).
//     enc written as packed bf16 pairs (u32) [L][P], nontemporal.
//   Phase B (MLP, MFMA): 256 pts/block, 4 waves; GEMM1->GELU->LDS(swizzled)
//     ->GEMM2->GELU->LDS->GEMM3 with mfma_f32_16x16x32_bf16. (~15us)
// Fallback: fused single-kernel VALU path if ws too small.

#define NLEV 16
#define TSIZE (1u << 19)
#define TMASK (TSIZE - 1u)
#define NXCD 8

typedef __attribute__((ext_vector_type(8))) short bf16x8;
typedef __attribute__((ext_vector_type(4))) float f32x4;

union U32x4 { unsigned u[4]; uint4 q; bf16x8 v; };

// round-to-nearest-even f32 -> bf16 bits
__device__ __forceinline__ unsigned bfr(float x) {
    unsigned u = __float_as_uint(x);
    return (u + 0x7FFFu + ((u >> 16) & 1u)) >> 16;
}

// exact-GELU via A&S 7.1.26 erf (|eps| <= 1.5e-7)
__device__ __forceinline__ float gelu_fast(float x) {
    float ax = fabsf(x) * 0.70710678118654752440f;
    float t  = __builtin_amdgcn_rcpf(fmaf(0.3275911f, ax, 1.0f));
    float p  = t * (0.254829592f + t * (-0.284496736f + t * (1.421413741f +
               t * (-1.453152027f + t * 1.061405429f))));
    float e  = __expf(-ax * ax);
    float er = fmaf(-p, e, 1.0f);
    er = copysignf(er, x);
    return 0.5f * x * (1.0f + er);
}

__device__ __forceinline__ float gelu_exact(float x) {
    return 0.5f * x * (1.0f + erff(x * 0.70710678118654752440f));
}

// ---------------- Phase A: hash-grid encode, XCD-pinned, paired loads ----------------
__global__ __launch_bounds__(256, 6) void ngp_encode(
    const float* __restrict__ inputs,   // [B,N,3]
    const float* __restrict__ latent,   // [B,1]
    const float* __restrict__ table,    // [16, 2^19, 2] f32
    unsigned* __restrict__ encb,        // [L][P] packed bf16 pair
    int P, int bplShift, int nShift)
{
    const int bid = blockIdx.x;
    const int xcd = bid & (NXCD - 1);
    const int j   = bid >> 3;
    const int l   = xcd * (NLEV / NXCD) + (j >> bplShift);
    const int p   = ((j & ((1 << bplShift) - 1)) << 8) + threadIdx.x;

    float x0 = inputs[p * 3 + 0];
    float x1 = inputs[p * 3 + 1];
    float x2 = inputs[p * 3 + 2];
    float x3 = latent[p >> nShift];
    x0 = (x0 + 1.0f) * 0.5f;
    x1 = (x1 + 1.0f) * 0.5f;
    x2 = (x2 + 1.0f) * 0.5f;
    x3 = (x3 + 1.0f) * 0.5f;

    const float LOG2S = (float)log2(1.3819);        // matches np.float32(np.log2(1.3819))
    const float s = exp2f((float)l * LOG2S) * 16.0f - 1.0f;

    const float px = fmaf(x0, s, 0.5f);
    const float py = fmaf(x1, s, 0.5f);
    const float pz = fmaf(x2, s, 0.5f);
    const float pw = fmaf(x3, s, 0.5f);
    const float fx = floorf(px), fy = floorf(py), fz = floorf(pz), fw = floorf(pw);
    const float rx = px - fx, ry = py - fy, rz = pz - fz, rw = pw - fw;

    const unsigned a0 = (unsigned)(int)fx;               const unsigned a1 = a0 + 1u;
    const unsigned b0 = (unsigned)(int)fy * 2654435761u; const unsigned b1v = b0 + 2654435761u;
    const unsigned c0 = (unsigned)(int)fz * 805459861u;  const unsigned c1 = c0 + 805459861u;
    const unsigned d0 = (unsigned)(int)fw * 3674653429u; const unsigned d1 = d0 + 3674653429u;

    const float wx0 = 1.0f - rx, wy0 = 1.0f - ry, wz0 = 1.0f - rz, ww0 = 1.0f - rw;
    const float wzw[4] = { wz0 * ww0, rz * ww0, wz0 * rw, rz * rw };

    const float2* __restrict__ tab2 = (const float2*)table + (unsigned)l * TSIZE;

    float acc0 = 0.0f, acc1 = 0.0f;

    if ((a0 & 1u) == 0u) {
        // even ix: corners (dim0=0, dim0=1) land on adjacent entries {2k,2k+1};
        // one aligned float4 (16B) per pair = 8 requests total.
        #pragma unroll
        for (int t = 0; t < 8; ++t) {
            const unsigned rest = ((t & 1) ? b1v : b0) ^ ((t & 2) ? c1 : c0)
                                ^ ((t & 4) ? d1 : d0);
            const float wrest = ((t & 1) ? ry : wy0) * wzw[t >> 1];
            const unsigned i0 = (a0 ^ rest) & TMASK;
            const float4 q = *(const float4*)(tab2 + (i0 & ~1u));
            const bool lowIs0 = (i0 & 1u) == 0u;
            const float v0x = lowIs0 ? q.x : q.z;
            const float v0y = lowIs0 ? q.y : q.w;
            const float v1x = lowIs0 ? q.z : q.x;
            const float v1y = lowIs0 ? q.w : q.y;
            const float we = wx0 * wrest;
            const float wo = rx  * wrest;
            acc0 = fmaf(we, v0x, fmaf(wo, v1x, acc0));
            acc1 = fmaf(we, v0y, fmaf(wo, v1y, acc1));
        }
    } else {
        // odd ix: no adjacency; 16 float2 loads.
        #pragma unroll
        for (int t = 0; t < 8; ++t) {
            const unsigned rest = ((t & 1) ? b1v : b0) ^ ((t & 2) ? c1 : c0)
                                ^ ((t & 4) ? d1 : d0);
            const float wrest = ((t & 1) ? ry : wy0) * wzw[t >> 1];
            const float2 v0 = tab2[(a0 ^ rest) & TMASK];
            const float2 v1 = tab2[(a1 ^ rest) & TMASK];
            const float we = wx0 * wrest;
            const float wo = rx  * wrest;
            acc0 = fmaf(we, v0.x, fmaf(wo, v1.x, acc0));
            acc1 = fmaf(we, v0.y, fmaf(wo, v1.y, acc1));
        }
    }
    __builtin_nontemporal_store(bfr(acc0) | (bfr(acc1) << 16), &encb[l * P + p]);
}

// ---------------- Phase B: MFMA MLP 32->64->64->3 ----------------
__global__ __launch_bounds__(256) void ngp_mlp_mfma(
    const unsigned* __restrict__ encb,  // [L][P] packed bf16 pair
    const float* __restrict__ W1, const float* __restrict__ b1,   // [32,64],[64]
    const float* __restrict__ W2, const float* __restrict__ b2,   // [64,64],[64]
    const float* __restrict__ W3, const float* __restrict__ b3,   // [64,3],[3]
    float* __restrict__ out, int P)
{
    __shared__ __align__(16) unsigned char sH[4 * 8192];  // 4 waves x 64pt x 64n x bf16

    const int tid  = threadIdx.x;
    const int w    = tid >> 6;
    const int lane = tid & 63;
    const int lo16 = lane & 15;
    const int hi4  = lane >> 4;          // lane group 0..3
    const int pbase = blockIdx.x * 256 + w * 64;
    char* const myH = (char*)sH + w * 8192;

    // ---- A-fragments (bf16) for W1^T, W2^T, W3^T ----
    bf16x8 w1f[4];
    #pragma unroll
    for (int mt = 0; mt < 4; ++mt) {
        const int m = mt * 16 + lo16;
        const int kg = hi4 * 8;
        bf16x8 f;
        #pragma unroll
        for (int j = 0; j < 4; ++j) {
            f[2 * j    ] = (short)bfr(W1[(kg + 2 * j    ) * 64 + m]);
            f[2 * j + 1] = (short)bfr(W1[(kg + 2 * j + 1) * 64 + m]);
        }
        w1f[mt] = f;
    }
    bf16x8 w2f[4][2];
    #pragma unroll
    for (int mt = 0; mt < 4; ++mt) {
        const int m = mt * 16 + lo16;
        #pragma unroll
        for (int kc = 0; kc < 2; ++kc) {
            const int kg = kc * 32 + hi4 * 8;
            bf16x8 f;
            #pragma unroll
            for (int j = 0; j < 4; ++j) {
                f[2 * j    ] = (short)bfr(W2[(kg + 2 * j    ) * 64 + m]);
                f[2 * j + 1] = (short)bfr(W2[(kg + 2 * j + 1) * 64 + m]);
            }
            w2f[mt][kc] = f;
        }
    }
    bf16x8 w3f[2];
    {
        const int m = (lo16 < 3) ? lo16 : 2;
        #pragma unroll
        for (int kc = 0; kc < 2; ++kc) {
            const int kg = kc * 32 + hi4 * 8;
            bf16x8 f;
            #pragma unroll
            for (int j = 0; j < 4; ++j) {
                f[2 * j    ] = (short)bfr(W3[(kg + 2 * j    ) * 3 + m]);
                f[2 * j + 1] = (short)bfr(W3[(kg + 2 * j + 1) * 3 + m]);
            }
            w3f[kc] = f;
        }
    }

    const f32x4 zero = {0.0f, 0.0f, 0.0f, 0.0f};

    // ---- GEMM1 ----
    f32x4 acc1[4][4];
    #pragma unroll
    for (int mt = 0; mt < 4; ++mt)
        #pragma unroll
        for (int nt = 0; nt < 4; ++nt) acc1[mt][nt] = zero;

    #pragma unroll
    for (int nt = 0; nt < 4; ++nt) {
        const int p = pbase + nt * 16 + lo16;
        const int lev0 = hi4 * 4;
        U32x4 bu;
        #pragma unroll
        for (int j = 0; j < 4; ++j) bu.u[j] = encb[(lev0 + j) * P + p];
        #pragma unroll
        for (int mt = 0; mt < 4; ++mt)
            acc1[mt][nt] = __builtin_amdgcn_mfma_f32_16x16x32_bf16(
                w1f[mt], bu.v, acc1[mt][nt], 0, 0, 0);
    }

    // ---- epilogue 1 ----
    float4 b1v[4];
    #pragma unroll
    for (int mt = 0; mt < 4; ++mt)
        b1v[mt] = *(const float4*)(b1 + mt * 16 + hi4 * 4);

    #pragma unroll
    for (int mt = 0; mt < 4; ++mt) {
        const int nb  = mt * 16 + hi4 * 4;
        const int blkb = nb >> 3;
        #pragma unroll
        for (int nt = 0; nt < 4; ++nt) {
            const f32x4 a = acc1[mt][nt];
            const float h0 = gelu_fast(a[0] + b1v[mt].x);
            const float h1 = gelu_fast(a[1] + b1v[mt].y);
            const float h2 = gelu_fast(a[2] + b1v[mt].z);
            const float h3 = gelu_fast(a[3] + b1v[mt].w);
            const int pl = nt * 16 + lo16;
            char* dst = myH + pl * 128 + ((blkb ^ (pl & 7)) * 16) + ((nb & 7) * 2);
            *(uint2*)dst = make_uint2(bfr(h0) | (bfr(h1) << 16),
                                      bfr(h2) | (bfr(h3) << 16));
        }
    }

    // ---- GEMM2 ----
    f32x4 acc2[4][4];
    #pragma unroll
    for (int mt = 0; mt < 4; ++mt)
        #pragma unroll
        for (int nt = 0; nt < 4; ++nt) acc2[mt][nt] = zero;

    #pragma unroll
    for (int kc = 0; kc < 2; ++kc) {
        #pragma unroll
        for (int nt = 0; nt < 4; ++nt) {
            const int pl = nt * 16 + lo16;
            const int kb = kc * 4 + hi4;
            const char* src = myH + pl * 128 + ((kb ^ (pl & 7)) * 16);
            U32x4 bu; bu.q = *(const uint4*)src;
            #pragma unroll
            for (int mt = 0; mt < 4; ++mt)
                acc2[mt][nt] = __builtin_amdgcn_mfma_f32_16x16x32_bf16(
                    w2f[mt][kc], bu.v, acc2[mt][nt], 0, 0, 0);
        }
    }

    // ---- epilogue 2 ----
    float4 b2v[4];
    #pragma unroll
    for (int mt = 0; mt < 4; ++mt)
        b2v[mt] = *(const float4*)(b2 + mt * 16 + hi4 * 4);

    #pragma unroll
    for (int mt = 0; mt < 4; ++mt) {
        const int nb  = mt * 16 + hi4 * 4;
        const int blkb = nb >> 3;
        #pragma unroll
        for (int nt = 0; nt < 4; ++nt) {
            const f32x4 a = acc2[mt][nt];
            const float h0 = gelu_fast(a[0] + b2v[mt].x);
            const float h1 = gelu_fast(a[1] + b2v[mt].y);
            const float h2 = gelu_fast(a[2] + b2v[mt].z);
            const float h3 = gelu_fast(a[3] + b2v[mt].w);
            const int pl = nt * 16 + lo16;
            char* dst = myH + pl * 128 + ((blkb ^ (pl & 7)) * 16) + ((nb & 7) * 2);
            *(uint2*)dst = make_uint2(bfr(h0) | (bfr(h1) << 16),
                                      bfr(h2) | (bfr(h3) << 16));
        }
    }

    // ---- GEMM3 ----
    f32x4 acc3[4];
    #pragma unroll
    for (int nt = 0; nt < 4; ++nt) acc3[nt] = zero;

    #pragma unroll
    for (int kc = 0; kc < 2; ++kc) {
        #pragma unroll
        for (int nt = 0; nt < 4; ++nt) {
            const int pl = nt * 16 + lo16;
            const int kb = kc * 4 + hi4;
            const char* src = myH + pl * 128 + ((kb ^ (pl & 7)) * 16);
            U32x4 bu; bu.q = *(const uint4*)src;
            acc3[nt] = __builtin_amdgcn_mfma_f32_16x16x32_bf16(
                w3f[kc], bu.v, acc3[nt], 0, 0, 0);
        }
    }

    const float b30 = b3[0], b31 = b3[1], b32 = b3[2];
    if (hi4 == 0) {
        #pragma unroll
        for (int nt = 0; nt < 4; ++nt) {
            const int p = pbase + nt * 16 + lo16;
            out[p * 3 + 0] = acc3[nt][0] + b30;
            out[p * 3 + 1] = acc3[nt][1] + b31;
            out[p * 3 + 2] = acc3[nt][2] + b32;
        }
    }
}

// ---------------- Fallback: fused single kernel (if ws too small) ----------------
__global__ __launch_bounds__(256) void ngp_fused(
    const float* __restrict__ inputs, const float* __restrict__ latent,
    const float* __restrict__ table,
    const float* __restrict__ W1, const float* __restrict__ b1,
    const float* __restrict__ W2, const float* __restrict__ b2,
    const float* __restrict__ W3, const float* __restrict__ b3,
    float* __restrict__ out)
{
    const int p = blockIdx.x * 256 + threadIdx.x;
    float x0 = inputs[p * 3 + 0];
    float x1 = inputs[p * 3 + 1];
    float x2 = inputs[p * 3 + 2];
    float x3 = latent[p >> 15];
    x0 = (x0 + 1.0f) * 0.5f; x1 = (x1 + 1.0f) * 0.5f;
    x2 = (x2 + 1.0f) * 0.5f; x3 = (x3 + 1.0f) * 0.5f;

    float h1[64];
    #pragma unroll
    for (int j = 0; j < 64; ++j) h1[j] = 0.0f;

    const float LOG2S = (float)log2(1.3819);
    const float2* __restrict__ tab2 = (const float2*)table;

    #pragma unroll 2
    for (int l = 0; l < NLEV; ++l) {
        const float s = exp2f((float)l * LOG2S) * 16.0f - 1.0f;
        const float px = fmaf(x0, s, 0.5f);
        const float py = fmaf(x1, s, 0.5f);
        const float pz = fmaf(x2, s, 0.5f);
        const float pw = fmaf(x3, s, 0.5f);
        const float fx = floorf(px), fy = floorf(py), fz = floorf(pz), fw = floorf(pw);
        const float rx = px - fx, ry = py - fy, rz = pz - fz, rw = pw - fw;
        const unsigned a0 = (unsigned)(int)fx;               const unsigned a1 = a0 + 1u;
        const unsigned b0 = (unsigned)(int)fy * 2654435761u; const unsigned b1v = b0 + 2654435761u;
        const unsigned c0 = (unsigned)(int)fz * 805459861u;  const unsigned c1 = c0 + 805459861u;
        const unsigned d0 = (unsigned)(int)fw * 3674653429u; const unsigned d1 = d0 + 3674653429u;
        const float wx0 = 1.0f - rx, wy0 = 1.0f - ry, wz0 = 1.0f - rz, ww0 = 1.0f - rw;
        const float wxy[4] = { wx0 * wy0, rx * wy0, wx0 * ry, rx * ry };
        const float wzw[4] = { wz0 * ww0, rz * ww0, wz0 * rw, rz * rw };
        const unsigned base = (unsigned)l * TSIZE;
        float acc0 = 0.0f, acc1 = 0.0f;
        #pragma unroll
        for (int c = 0; c < 16; ++c) {
            unsigned h = ((c & 1) ? a1 : a0) ^ ((c & 2) ? b1v : b0)
                       ^ ((c & 4) ? c1 : c0) ^ ((c & 8) ? d1 : d0);
            const float2 v = tab2[base + (h & TMASK)];
            const float wgt = wxy[c & 3] * wzw[c >> 2];
            acc0 = fmaf(wgt, v.x, acc0);
            acc1 = fmaf(wgt, v.y, acc1);
        }
        const float* __restrict__ w0 = W1 + (2 * l) * 64;
        const float* __restrict__ w1 = W1 + (2 * l + 1) * 64;
        #pragma unroll
        for (int j = 0; j < 64; ++j) {
            h1[j] = fmaf(acc0, w0[j], fmaf(acc1, w1[j], h1[j]));
        }
    }
    #pragma unroll
    for (int j = 0; j < 64; ++j) h1[j] = gelu_exact(h1[j] + b1[j]);

    float col0 = b3[0], col1 = b3[1], col2 = b3[2];
    #pragma unroll 1
    for (int ch = 0; ch < 8; ++ch) {
        float acc[8];
        #pragma unroll
        for (int k = 0; k < 8; ++k) acc[k] = b2[ch * 8 + k];
        #pragma unroll
        for (int i = 0; i < 64; ++i) {
            const float hv = h1[i];
            const float* __restrict__ wr = W2 + i * 64 + ch * 8;
            #pragma unroll
            for (int k = 0; k < 8; ++k) acc[k] = fmaf(hv, wr[k], acc[k]);
        }
        #pragma unroll
        for (int k = 0; k < 8; ++k) {
            const float g = gelu_exact(acc[k]);
            const int j2 = ch * 8 + k;
            col0 = fmaf(g, W3[j2 * 3 + 0], col0);
            col1 = fmaf(g, W3[j2 * 3 + 1], col1);
            col2 = fmaf(g, W3[j2 * 3 + 2], col2);
        }
    }
    out[p * 3 + 0] = col0;
    out[p * 3 + 1] = col1;
    out[p * 3 + 2] = col2;
}

extern "C" void kernel_launch(void* const* d_in, const int* in_sizes, int n_in,
                              void* d_out, int out_size, void* d_ws, size_t ws_size,
                              hipStream_t stream) {
    const float* inputs = (const float*)d_in[0];
    const float* latent = (const float*)d_in[1];
    const float* table  = (const float*)d_in[2];
    const float* W1 = (const float*)d_in[3];
    const float* b1 = (const float*)d_in[4];
    const float* W2 = (const float*)d_in[5];
    const float* b2 = (const float*)d_in[6];
    const float* W3 = (const float*)d_in[7];
    const float* b3 = (const float*)d_in[8];
    float* out = (float*)d_out;

    const int P = in_sizes[0] / 3;              // 262144
    const int B = in_sizes[1];                  // 8
    const int N = P / B;                        // 32768
    const int nShift = 31 - __builtin_clz(N);   // 15
    const int bpl = P / 256;                    // 1024 blocks per level
    const int bplShift = 31 - __builtin_clz(bpl);

    const size_t encBytes = (size_t)P * NLEV * sizeof(unsigned);  // 16.8 MB
    const bool shapeOK = (P & 255) == 0 && (bpl & (bpl - 1)) == 0 &&
                         (N & (N - 1)) == 0 && bpl >= 8;

    if (shapeOK && ws_size >= encBytes) {
        unsigned* encb = (unsigned*)d_ws;
        ngp_encode<<<dim3(bpl * NLEV), dim3(256), 0, stream>>>(
            inputs, latent, table, encb, P, bplShift, nShift);
        ngp_mlp_mfma<<<dim3(P / 256), dim3(256), 0, stream>>>(
            encb, W1, b1, W2, b2, W3, b3, out, P);
    } else {
        ngp_fused<<<dim3(P / 256), dim3(256), 0, stream>>>(
            inputs, latent, table, W1, b1, W2, b2, W3, b3, out);
    }
}